// Round 10
// baseline (204.175 us; speedup 1.0000x reference)
//
#include <hip/hip_runtime.h>
#include <hip/hip_cooperative_groups.h>

namespace cg = cooperative_groups;

#define BATCH     4096
#define NCTX      8
#define NK        6
#define VDIM      256
#define NWORDS    50000
#define NPAIRS    (BATCH * NK)              // 24576
#define CBLK      16                        // O columns per bin
#define NBINS     (NWORDS / CBLK)           // 3125 exactly
#define CAP       48                        // pairs per bin (mean 7.86)
#define TSTRIDE   (VDIM + 2)                // 258: write-side 2-way (free), read contiguous
#define GRID      1024                      // co-resident: 4 blocks/CU x 256 CU
#define PPX       (NPAIRS / GRID)           // 24 pairs binned per block

#define XBYTES    ((size_t)BATCH * VDIM * sizeof(float))   // 4 MB

// ---------------------------------------------------------------------------
// Single cooperative kernel.
//  phase 0: zero bin counters
//  phase 1: x[b,:] = D[doc[b]] + sum_c W[ctx[b,c]] (1 row/wave) + bin 24 pairs
//  phase 2: grid-stride over bins, double-buffered LDS O-tiles, metadata/x
//           prefetched one bin ahead. Pair phase is pure LDS + VALU.
// ---------------------------------------------------------------------------
__global__ __launch_bounds__(256, 4)
void DM_42417097016803_coop(const int* __restrict__ ctx,
                            const int* __restrict__ doc,
                            const int* __restrict__ tgt,
                            const float* __restrict__ D,
                            const float* __restrict__ W,
                            const float* __restrict__ O,
                            float* __restrict__ out,
                            float* __restrict__ x,
                            int* __restrict__ counts,
                            int* __restrict__ bins)
{
    __shared__ float tile[2][CBLK][TSTRIDE];   // 33 KB -> 4 blocks/CU

    cg::grid_group grid = cg::this_grid();

    const int tid  = threadIdx.x;
    const int bid  = blockIdx.x;
    const int wave = tid >> 6;
    const int lane = tid & 63;

    // ---------------- phase 0: zero counters ----------------
    {
        const int g = bid * 256 + tid;
        if (g < NBINS) counts[g] = 0;
    }
    grid.sync();

    // ---------------- phase 1: xbuild + bin ----------------
    if (tid < PPX) {
        const int i   = bid * PPX + tid;
        const int c   = tgt[i];
        const int bin = c >> 4;                          // CBLK = 16
        const int pos = atomicAdd(&counts[bin], 1);
        if (pos < CAP) bins[bin * CAP + pos] = (i << 4) | (c & (CBLK - 1));
    }
    {
        const int b = bid * 4 + wave;                    // 4096 rows over 1024 blocks
        const float4* __restrict__ D4 = reinterpret_cast<const float4*>(D);
        const float4* __restrict__ W4 = reinterpret_cast<const float4*>(W);
        float4* __restrict__       x4 = reinterpret_cast<float4*>(x);

        const int docid = doc[b];
        float4 v = D4[(size_t)docid * 64 + lane];
#pragma unroll
        for (int c = 0; c < NCTX; ++c) {
            const int id = ctx[b * NCTX + c];
            const float4 w = W4[(size_t)id * 64 + lane];
            v.x += w.x; v.y += w.y; v.z += w.z; v.w += w.w;
        }
        x4[(size_t)b * 64 + lane] = v;
    }
    grid.sync();

    // ---------------- phase 2: score ----------------
    const float4* __restrict__ x4 = reinterpret_cast<const float4*>(x);
    const int c4  = tid & 3;                 // float4-column within 16-col tile
    const int row = tid >> 2;                // 0..63

    // prologue: bin0 metadata + tile -> LDS[0]
    int np = counts[bid];  if (np > CAP) np = CAP;
    int pk[4]; float4 xv[4]; int nA = 0;
#pragma unroll
    for (int j = 0; j < 4; ++j) {
        const int p = wave + 4 * j;
        if (p < np) {
            pk[j] = bins[bid * CAP + p];
            xv[j] = x4[(size_t)((unsigned)(pk[j] >> 4) / NK) * 64 + lane];
            nA = j + 1;
        }
    }
    {
        float4 r[4];
#pragma unroll
        for (int rb = 0; rb < 4; ++rb)
            r[rb] = *reinterpret_cast<const float4*>(
                &O[(size_t)(rb * 64 + row) * NWORDS + bid * CBLK + c4 * 4]);
#pragma unroll
        for (int rb = 0; rb < 4; ++rb) {
            const int t = rb * 64 + row;
            tile[0][c4 * 4 + 0][t] = r[rb].x;
            tile[0][c4 * 4 + 1][t] = r[rb].y;
            tile[0][c4 * 4 + 2][t] = r[rb].z;
            tile[0][c4 * 4 + 3][t] = r[rb].w;
        }
    }
    __syncthreads();

    int cur = 0;
    for (int bin = bid; bin < NBINS; bin += GRID) {
        const int  nxt  = bin + GRID;
        const bool hasn = (nxt < NBINS);

        // (1) next tile loads into registers (independent; in flight all phase)
        float4 r[4];
        if (hasn) {
#pragma unroll
            for (int rb = 0; rb < 4; ++rb)
                r[rb] = *reinterpret_cast<const float4*>(
                    &O[(size_t)(rb * 64 + row) * NWORDS + nxt * CBLK + c4 * 4]);
        }

        // (2) next metadata + x prefetch
        int npN = 0, pkN[4]; float4 xvN[4]; int nAN = 0;
        if (hasn) {
            npN = counts[nxt]; if (npN > CAP) npN = CAP;
#pragma unroll
            for (int j = 0; j < 4; ++j) {
                const int p = wave + 4 * j;
                if (p < npN) {
                    pkN[j] = bins[nxt * CAP + p];
                    xvN[j] = x4[(size_t)((unsigned)(pkN[j] >> 4) / NK) * 64 + lane];
                    nAN = j + 1;
                }
            }
        }

        // (3) pair phase for current bin: pure LDS + VALU
#pragma unroll
        for (int j = 0; j < 4; ++j) {
            if (j < nA) {
                const int i = pk[j] >> 4;
                const int c = pk[j] & (CBLK - 1);
                const float4 ov =
                    *reinterpret_cast<const float4*>(&tile[cur][c][lane * 4]);
                float d = xv[j].x * ov.x + xv[j].y * ov.y
                        + xv[j].z * ov.z + xv[j].w * ov.w;
#pragma unroll
                for (int off = 32; off >= 1; off >>= 1)
                    d += __shfl_down(d, off, 64);
                if (lane == 0) out[i] = d;
            }
        }
        // residual (np > 16; ~0.3% of bins)
        for (int p = 16 + wave; p < np; p += 4) {
            const int pkr = bins[bin * CAP + p];
            const int i = pkr >> 4;
            const int c = pkr & (CBLK - 1);
            const float4 xvr = x4[(size_t)((unsigned)i / NK) * 64 + lane];
            const float4 ov =
                *reinterpret_cast<const float4*>(&tile[cur][c][lane * 4]);
            float d = xvr.x * ov.x + xvr.y * ov.y + xvr.z * ov.z + xvr.w * ov.w;
#pragma unroll
            for (int off = 32; off >= 1; off >>= 1)
                d += __shfl_down(d, off, 64);
            if (lane == 0) out[i] = d;
        }

        // (4) next tile regs -> LDS[cur^1]
        if (hasn) {
#pragma unroll
            for (int rb = 0; rb < 4; ++rb) {
                const int t = rb * 64 + row;
                tile[cur ^ 1][c4 * 4 + 0][t] = r[rb].x;
                tile[cur ^ 1][c4 * 4 + 1][t] = r[rb].y;
                tile[cur ^ 1][c4 * 4 + 2][t] = r[rb].z;
                tile[cur ^ 1][c4 * 4 + 3][t] = r[rb].w;
            }
        }
        __syncthreads();

        // (5) rotate
        np = npN; nA = nAN;
#pragma unroll
        for (int j = 0; j < 4; ++j) { pk[j] = pkN[j]; xv[j] = xvN[j]; }
        cur ^= 1;
    }
}

// ---------------------------------------------------------------------------
// Stream-ordered fallback path (R6/R9 structure) in case cooperative launch
// is unavailable.
// ---------------------------------------------------------------------------
__global__ __launch_bounds__(256)
void DM_42417097016803_xbin(const int* __restrict__ ctx,
                            const int* __restrict__ doc,
                            const int* __restrict__ tgt,
                            const float* __restrict__ D,
                            const float* __restrict__ W,
                            float* __restrict__ x,
                            int* __restrict__ counts,
                            int* __restrict__ bins)
{
    const int tid = threadIdx.x;
    if (tid < PPX) {
        const int i   = blockIdx.x * PPX + tid;
        const int c   = tgt[i];
        const int bin = c >> 4;
        const int pos = atomicAdd(&counts[bin], 1);
        if (pos < CAP) bins[bin * CAP + pos] = (i << 4) | (c & (CBLK - 1));
    }
    const int wave = tid >> 6;
    const int lane = tid & 63;
    const int b    = blockIdx.x * 4 + wave;

    const float4* __restrict__ D4 = reinterpret_cast<const float4*>(D);
    const float4* __restrict__ W4 = reinterpret_cast<const float4*>(W);
    float4* __restrict__       x4 = reinterpret_cast<float4*>(x);

    const int docid = doc[b];
    float4 v = D4[(size_t)docid * 64 + lane];
#pragma unroll
    for (int c = 0; c < NCTX; ++c) {
        const int id = ctx[b * NCTX + c];
        const float4 w = W4[(size_t)id * 64 + lane];
        v.x += w.x; v.y += w.y; v.z += w.z; v.w += w.w;
    }
    x4[(size_t)b * 64 + lane] = v;
}

__global__ __launch_bounds__(256, 8)
void DM_42417097016803_score(const int* __restrict__ counts,
                             const int* __restrict__ bins,
                             const float* __restrict__ x,
                             const float* __restrict__ O,
                             float* __restrict__ out)
{
    __shared__ float tile[CBLK][TSTRIDE];

    const int tid  = threadIdx.x;
    const int bid  = blockIdx.x;
    const int c0   = bid * CBLK;
    const int wave = tid >> 6;
    const int lane = tid & 63;

    int np = counts[bid];
    if (np > CAP) np = CAP;

    const float4* __restrict__ x4 = reinterpret_cast<const float4*>(x);
    const int* __restrict__ mybins = &bins[bid * CAP];

    int pkA[4]; float4 xvA[4]; int nA = 0;
#pragma unroll
    for (int j = 0; j < 4; ++j) {
        const int p = wave + 4 * j;
        if (p < np) {
            const int pk = mybins[p];
            pkA[j] = pk;
            xvA[j] = x4[(size_t)((unsigned)(pk >> 4) / NK) * 64 + lane];
            nA = j + 1;
        }
    }

    const int c4  = tid & 3;
    const int row = tid >> 2;
    float4 r[4];
#pragma unroll
    for (int rb = 0; rb < 4; ++rb)
        r[rb] = *reinterpret_cast<const float4*>(
            &O[(size_t)(rb * 64 + row) * NWORDS + c0 + c4 * 4]);
#pragma unroll
    for (int rb = 0; rb < 4; ++rb) {
        const int t = rb * 64 + row;
        tile[c4 * 4 + 0][t] = r[rb].x;
        tile[c4 * 4 + 1][t] = r[rb].y;
        tile[c4 * 4 + 2][t] = r[rb].z;
        tile[c4 * 4 + 3][t] = r[rb].w;
    }
    __syncthreads();

#pragma unroll
    for (int j = 0; j < 4; ++j) {
        if (j < nA) {
            const int i = pkA[j] >> 4;
            const int c = pkA[j] & (CBLK - 1);
            const float4 ov = *reinterpret_cast<const float4*>(&tile[c][lane * 4]);
            float d = xvA[j].x * ov.x + xvA[j].y * ov.y
                    + xvA[j].z * ov.z + xvA[j].w * ov.w;
#pragma unroll
            for (int off = 32; off >= 1; off >>= 1)
                d += __shfl_down(d, off, 64);
            if (lane == 0) out[i] = d;
        }
    }
    for (int p = 16 + wave; p < np; p += 4) {
        const int pk = mybins[p];
        const int i = pk >> 4;
        const int c = pk & (CBLK - 1);
        const float4 xv = x4[(size_t)((unsigned)i / NK) * 64 + lane];
        const float4 ov = *reinterpret_cast<const float4*>(&tile[c][lane * 4]);
        float d = xv.x * ov.x + xv.y * ov.y + xv.z * ov.z + xv.w * ov.w;
#pragma unroll
        for (int off = 32; off >= 1; off >>= 1)
            d += __shfl_down(d, off, 64);
        if (lane == 0) out[i] = d;
    }
}

extern "C" void kernel_launch(void* const* d_in, const int* in_sizes, int n_in,
                              void* d_out, int out_size, void* d_ws, size_t ws_size,
                              hipStream_t stream)
{
    const int*   ctx = (const int*)d_in[0];   // (4096, 8)
    const int*   doc = (const int*)d_in[1];   // (4096,)
    const int*   tid = (const int*)d_in[2];   // (4096, 6)
    const float* D   = (const float*)d_in[3]; // (100000, 256)
    const float* W   = (const float*)d_in[4]; // (50000, 256)
    const float* O   = (const float*)d_in[5]; // (256, 50000)
    float*       out = (float*)d_out;         // (4096, 6)

    const size_t count_bytes = (size_t)NBINS * sizeof(int);          // 12.5 KB
    const size_t bin_bytes   = (size_t)NBINS * CAP * sizeof(int);    // 600 KB
    const size_t need        = XBYTES + count_bytes + bin_bytes;

    if (ws_size < need) return;   // (ws is 400 MB in practice)

    float* x      = (float*)d_ws;
    int*   counts = (int*)((char*)d_ws + XBYTES);
    int*   bins   = counts + NBINS;

    void* args[] = { (void*)&ctx, (void*)&doc, (void*)&tid,
                     (void*)&D, (void*)&W, (void*)&O,
                     (void*)&out, (void*)&x, (void*)&counts, (void*)&bins };

    hipError_t e = hipLaunchCooperativeKernel(
        (const void*)DM_42417097016803_coop,
        dim3(GRID), dim3(256), args, 0, stream);

    if (e != hipSuccess) {
        // stream-ordered fallback (R6-style, 3 dispatches)
        hipMemsetAsync(counts, 0, count_bytes, stream);
        DM_42417097016803_xbin<<<GRID, 256, 0, stream>>>(
            ctx, doc, tid, D, W, x, counts, bins);
        DM_42417097016803_score<<<NBINS, 256, 0, stream>>>(
            counts, bins, x, O, out);
    }
}